// Round 2
// baseline (583.410 us; speedup 1.0000x reference)
//
#include <hip/hip_runtime.h>
#include <hip/hip_bf16.h>
#include <stdint.h>

#define BB 4
#define NN 2048
#define CC 1024
#define HH 16
#define DD 64
#define NEGV (-1e9f)

typedef __attribute__((ext_vector_type(8))) short bf16x8;
typedef __attribute__((ext_vector_type(4))) float f32x4;

// ---------- small helpers ----------
__device__ __forceinline__ unsigned short f2bf(float x) {
  uint32_t u = __float_as_uint(x);
  uint32_t r = (u + 0x7FFFu + ((u >> 16) & 1u)) >> 16;   // RNE
  return (unsigned short)r;
}
__device__ __forceinline__ float bf2f(unsigned short v) {
  return __uint_as_float(((uint32_t)v) << 16);
}
__device__ __forceinline__ float load_in_f(const void* p, size_t idx, int f32in) {
  if (f32in) return ((const float*)p)[idx];
  return bf2f(((const uint16_t*)p)[idx]);
}
// async global->LDS, 16B per lane; lds ptr must be the wave-uniform base
__device__ __forceinline__ void gload16(uint16_t* lds_base, const uint16_t* gsrc) {
  __builtin_amdgcn_global_load_lds(
      (const __attribute__((address_space(1))) uint32_t*)(const void*)gsrc,
      (__attribute__((address_space(3))) uint32_t*)(void*)lds_base,
      16, 0, 0);
}

// ---------- dtype detection ----------
// flags[0]: 1 => float inputs are fp32 buffers; 0 => packed bf16 buffers.
// Classifier: count "sane bf16" half-words in the first 128 words of query.
//   packed bf16: ~100% sane; full fp32: ~56%; bf16-rounded fp32: ~50%.
__global__ void detect_kernel(const uint32_t* __restrict__ q,
                              const uint32_t* __restrict__ m,
                              int* __restrict__ flags) {
  if (threadIdx.x == 0 && blockIdx.x == 0) {
    int sane = 0;
    for (int i = 0; i < 128; ++i) {
      uint32_t w = q[i];
      int e0 = (int)((w >> 7) & 0xFFu);          // exponent of low half-word
      int e1 = (int)((w >> 23) & 0xFFu);         // exponent of high half-word
      sane += (e0 >= 0x70 && e0 <= 0x8F) ? 1 : 0;
      sane += (e1 >= 0x70 && e1 <= 0x8F) ? 1 : 0;
    }
    flags[0] = (sane >= 208) ? 0 : 1;
    int allsmall = 1;
    for (int i = 0; i < 16; ++i) if (m[i] > 1u) allsmall = 0;
    flags[1] = allsmall;                          // 1 => mask is int32
  }
}

// ---------- conversions ----------
__global__ void conv_bf16(const void* __restrict__ src, uint16_t* __restrict__ dst,
                          int n, const int* __restrict__ flags) {
  const int f32in = flags[0];
  int idx = blockIdx.x * blockDim.x + threadIdx.x;
  const int total = n >> 2;
  const int stride = gridDim.x * blockDim.x;
  if (f32in) {
    const float4* s = (const float4*)src;
    for (; idx < total; idx += stride) {
      float4 v = s[idx];
      ushort4 o;
      o.x = f2bf(v.x); o.y = f2bf(v.y); o.z = f2bf(v.z); o.w = f2bf(v.w);
      ((ushort4*)dst)[idx] = o;
    }
  } else {
    const ushort4* s = (const ushort4*)src;
    for (; idx < total; idx += stride) ((ushort4*)dst)[idx] = s[idx];
  }
}

__global__ void conv_ratio(const void* __restrict__ src, float* __restrict__ dst,
                           int n, const int* __restrict__ flags) {
  const int f32in = flags[0];
  int idx = blockIdx.x * blockDim.x + threadIdx.x;
  const int stride = gridDim.x * blockDim.x;
  for (; idx < n; idx += stride) dst[idx] = load_in_f(src, idx, f32in);
}

__global__ void conv_mask(const void* __restrict__ src, uint8_t* __restrict__ dst,
                          int n, const int* __restrict__ flags) {
  const int isint = flags[1];
  int idx = blockIdx.x * blockDim.x + threadIdx.x;
  const int total = n >> 2;
  const int stride = gridDim.x * blockDim.x;
  if (isint) {
    const int4* s = (const int4*)src;
    for (; idx < total; idx += stride) {
      int4 v = s[idx];
      uchar4 o;
      o.x = (uint8_t)(v.x != 0); o.y = (uint8_t)(v.y != 0);
      o.z = (uint8_t)(v.z != 0); o.w = (uint8_t)(v.w != 0);
      ((uchar4*)dst)[idx] = o;
    }
  } else {
    const uchar4* s = (const uchar4*)src;
    for (; idx < total; idx += stride) ((uchar4*)dst)[idx] = s[idx];
  }
}

// ---------- W transpose + bf16 convert: Wt[n][k] = W[k][n] ----------
__global__ __launch_bounds__(256)
void transW(const void* w0, const void* w1, const void* w2, const void* w3,
            uint16_t* __restrict__ wt, const int* __restrict__ flags) {
  const int f32in = flags[0];
  const void* src = (blockIdx.z == 0) ? w0 : (blockIdx.z == 1) ? w1
                   : (blockIdx.z == 2) ? w2 : w3;
  uint16_t* dst = wt + (size_t)blockIdx.z * CC * CC;
  __shared__ float t[32][33];
  const int tx = threadIdx.x, ty = threadIdx.y;
  const int n0 = blockIdx.x * 32, k0 = blockIdx.y * 32;
#pragma unroll
  for (int r = 0; r < 4; ++r) {
    int k = k0 + ty + r * 8;
    t[ty + r * 8][tx] = load_in_f(src, (size_t)k * CC + n0 + tx, f32in);
  }
  __syncthreads();
#pragma unroll
  for (int r = 0; r < 4; ++r) {
    int n = n0 + ty + r * 8;
    dst[(size_t)n * CC + k0 + tx] = f2bf(t[tx][ty + r * 8]);
  }
}

// ---------- 128x128x(BK=32) bf16 MFMA GEMM, M=8192 N=1024 K=1024 ----------
// A [M][1024] bf16 row-major; Bt [N][1024] bf16 row-major (= W^T)
// MODE 0: out = qk layout [B,H,N,D]; MODE 1: out = vt layout [B,H,D,N]
// MODE 2: out fp32 [M][1024] = acc + resid (residual, raw input dtype)
template <int MODE>
__global__ __launch_bounds__(256, 2)
void gemm128(const uint16_t* __restrict__ A, const uint16_t* __restrict__ Bt,
             void* __restrict__ out, const void* __restrict__ resid,
             const int* __restrict__ flags) {
  __shared__ uint16_t As[128 * 32];
  __shared__ uint16_t Bs[128 * 32];
  const int tid = threadIdx.x;
  const int wid = tid >> 6, lane = tid & 63;
  const int g = lane >> 4, c = lane & 15;
  const int m0 = blockIdx.x * 128, n0 = blockIdx.y * 128;
  const int wr = wid >> 1, wc = wid & 1;
  f32x4 acc[4][4] = {};
  for (int k0 = 0; k0 < 1024; k0 += 32) {
    __syncthreads();
#pragma unroll
    for (int is = 0; is < 2; ++is) {
      int sb = is * 256 + wid * 64;
      int s = sb + lane;
      int r = s >> 2, kp = s & 3;
      gload16(&As[sb * 8], A + (size_t)(m0 + r) * 1024 + k0 + kp * 8);
      gload16(&Bs[sb * 8], Bt + (size_t)(n0 + r) * 1024 + k0 + kp * 8);
    }
    __syncthreads();
    bf16x8 a[4], b[4];
#pragma unroll
    for (int mi = 0; mi < 4; ++mi)
      a[mi] = *(const bf16x8*)&As[(wr * 64 + mi * 16 + c) * 32 + g * 8];
#pragma unroll
    for (int ni = 0; ni < 4; ++ni)
      b[ni] = *(const bf16x8*)&Bs[(wc * 64 + ni * 16 + c) * 32 + g * 8];
#pragma unroll
    for (int mi = 0; mi < 4; ++mi)
#pragma unroll
      for (int ni = 0; ni < 4; ++ni)
        acc[mi][ni] = __builtin_amdgcn_mfma_f32_16x16x32_bf16(a[mi], b[ni], acc[mi][ni], 0, 0, 0);
  }
  const int f32in = flags[0];
#pragma unroll
  for (int mi = 0; mi < 4; ++mi)
#pragma unroll
    for (int ni = 0; ni < 4; ++ni)
#pragma unroll
      for (int r = 0; r < 4; ++r) {
        int mrow = m0 + wr * 64 + mi * 16 + g * 4 + r;
        int ncol = n0 + wc * 64 + ni * 16 + c;
        float v = acc[mi][ni][r];
        if (MODE == 0) {
          int b_ = mrow >> 11, i = mrow & 2047, h = ncol >> 6, d = ncol & 63;
          ((uint16_t*)out)[((size_t)(b_ * 16 + h) * 2048 + i) * 64 + d] = f2bf(v);
        } else if (MODE == 1) {
          int b_ = mrow >> 11, i = mrow & 2047, h = ncol >> 6, d = ncol & 63;
          ((uint16_t*)out)[((size_t)(b_ * 16 + h) * 64 + d) * 2048 + i] = f2bf(v);
        } else {
          size_t idx = (size_t)mrow * 1024 + ncol;
          ((float*)out)[idx] = v + load_in_f(resid, idx, f32in);
        }
      }
}

// ---------- pass 1: column (query-axis) softmax stats Z_j = M_j + ln L_j ----------
__global__ __launch_bounds__(256, 2)
void attn_stats(const uint16_t* __restrict__ qb, const uint16_t* __restrict__ kb,
                const uint8_t* __restrict__ maskc, const float* __restrict__ ratio_f,
                float* __restrict__ Zbuf) {
  __shared__ uint16_t Ks[2][128 * 32];
  __shared__ uint16_t Qs[2][128 * 32];
  __shared__ float redM[4][128];
  __shared__ float redL[4][128];
  const int tid = threadIdx.x, wid = tid >> 6, lane = tid & 63;
  const int g = lane >> 4, c = lane & 15;
  const int bh = blockIdx.x, b_ = bh >> 4;
  const int j0 = blockIdx.y * 128;
  const uint16_t* Kg = kb + (size_t)bh * NN * DD + (size_t)j0 * DD;
  const uint16_t* Qg = qb + (size_t)bh * NN * DD;
  const uint8_t* Mg = maskc + (size_t)b_ * NN * NN;
#pragma unroll
  for (int hf = 0; hf < 2; ++hf)
#pragma unroll
    for (int is = 0; is < 2; ++is) {
      int sb = is * 256 + wid * 64;
      int s = sb + lane;
      int r = s >> 2, kp = s & 3;
      gload16(&Ks[hf][sb * 8], Kg + (size_t)r * 64 + hf * 32 + kp * 8);
    }
  float rj[8], m_[8], l_[8];
#pragma unroll
  for (int nj = 0; nj < 8; ++nj) {
    rj[nj] = ratio_f[b_ * NN + j0 + nj * 16 + c];
    m_[nj] = -3.4e38f;
    l_[nj] = 0.f;
  }
  for (int i0 = 0; i0 < NN; i0 += 128) {
    __syncthreads();
#pragma unroll
    for (int hf = 0; hf < 2; ++hf)
#pragma unroll
      for (int is = 0; is < 2; ++is) {
        int sb = is * 256 + wid * 64;
        int s = sb + lane;
        int r = s >> 2, kp = s & 3;
        gload16(&Qs[hf][sb * 8], Qg + (size_t)(i0 + r) * 64 + hf * 32 + kp * 8);
      }
    __syncthreads();
    f32x4 sacc[2][8] = {};
#pragma unroll
    for (int ks = 0; ks < 2; ++ks) {
      bf16x8 a[2], bfr[8];
#pragma unroll
      for (int mi = 0; mi < 2; ++mi)
        a[mi] = *(const bf16x8*)&Qs[ks][(wid * 32 + mi * 16 + c) * 32 + g * 8];
#pragma unroll
      for (int nj = 0; nj < 8; ++nj)
        bfr[nj] = *(const bf16x8*)&Ks[ks][(nj * 16 + c) * 32 + g * 8];
#pragma unroll
      for (int mi = 0; mi < 2; ++mi)
#pragma unroll
        for (int nj = 0; nj < 8; ++nj)
          sacc[mi][nj] = __builtin_amdgcn_mfma_f32_16x16x32_bf16(a[mi], bfr[nj], sacc[mi][nj], 0, 0, 0);
    }
#pragma unroll
    for (int nj = 0; nj < 8; ++nj) {
      int j = j0 + nj * 16 + c;
      float sv[2][4];
      float vmax = -3.4e38f;
#pragma unroll
      for (int mi = 0; mi < 2; ++mi)
#pragma unroll
        for (int r = 0; r < 4; ++r) {
          int i = i0 + wid * 32 + mi * 16 + g * 4 + r;
          float s = sacc[mi][nj][r] * 0.125f;
          if (Mg[(size_t)i * NN + j]) s = NEGV;
          s *= rj[nj];
          sv[mi][r] = s;
          vmax = fmaxf(vmax, s);
        }
      vmax = fmaxf(vmax, __shfl_xor(vmax, 16));
      vmax = fmaxf(vmax, __shfl_xor(vmax, 32));
      float mnew = fmaxf(m_[nj], vmax);
      float ssum = 0.f;
#pragma unroll
      for (int mi = 0; mi < 2; ++mi)
#pragma unroll
        for (int r = 0; r < 4; ++r)
          ssum += __expf(sv[mi][r] - mnew);
      ssum += __shfl_xor(ssum, 16);
      ssum += __shfl_xor(ssum, 32);
      l_[nj] = l_[nj] * __expf(m_[nj] - mnew) + ssum;
      m_[nj] = mnew;
    }
  }
#pragma unroll
  for (int nj = 0; nj < 8; ++nj)
    if (g == 0) { redM[wid][nj * 16 + c] = m_[nj]; redL[wid][nj * 16 + c] = l_[nj]; }
  __syncthreads();
  if (tid < 128) {
    float M = redM[0][tid];
    for (int w = 1; w < 4; ++w) M = fmaxf(M, redM[w][tid]);
    float L = 0.f;
    for (int w = 0; w < 4; ++w) L += redL[w][tid] * __expf(redM[w][tid] - M);
    Zbuf[(size_t)bh * NN + j0 + tid] = M + logf(L);
  }
}

// ---------- pass 2: weights + PV -> ctx [B,N,H*D] bf16 ----------
__global__ __launch_bounds__(256, 2)
void attn_pv(const uint16_t* __restrict__ qb, const uint16_t* __restrict__ kb,
             const uint16_t* __restrict__ vt, const uint8_t* __restrict__ maskc,
             const float* __restrict__ ratio_f, const float* __restrict__ Zbuf,
             uint16_t* __restrict__ ctxr) {
  __shared__ uint16_t Qs[2][128 * 32];
  __shared__ uint16_t Ks[2][128 * 32];
  __shared__ uint16_t Vs[4][64 * 32];
  __shared__ uint16_t Ps[4][128 * 32];
  const int tid = threadIdx.x, wid = tid >> 6, lane = tid & 63;
  const int g = lane >> 4, c = lane & 15;
  const int bh = blockIdx.x, b_ = bh >> 4, h = bh & 15;
  const int i0 = blockIdx.y * 128;
  const uint16_t* Qg = qb + (size_t)bh * NN * DD;
  const uint16_t* Kg = kb + (size_t)bh * NN * DD;
  const uint16_t* Vg = vt + (size_t)bh * DD * NN;
  const uint8_t* Mg = maskc + (size_t)b_ * NN * NN;
#pragma unroll
  for (int hf = 0; hf < 2; ++hf)
#pragma unroll
    for (int is = 0; is < 2; ++is) {
      int sb = is * 256 + wid * 64;
      int s = sb + lane;
      int r = s >> 2, kp = s & 3;
      gload16(&Qs[hf][sb * 8], Qg + (size_t)(i0 + r) * 64 + hf * 32 + kp * 8);
    }
  f32x4 cacc[2][4] = {};
  for (int j0 = 0; j0 < NN; j0 += 128) {
    __syncthreads();
#pragma unroll
    for (int hf = 0; hf < 2; ++hf)
#pragma unroll
      for (int is = 0; is < 2; ++is) {
        int sb = is * 256 + wid * 64;
        int s = sb + lane;
        int r = s >> 2, kp = s & 3;
        gload16(&Ks[hf][sb * 8], Kg + (size_t)(j0 + r) * 64 + hf * 32 + kp * 8);
      }
#pragma unroll
    for (int q = 0; q < 4; ++q) {
      int sb = wid * 64;
      int s = sb + lane;
      int d = s >> 2, kp = s & 3;
      gload16(&Vs[q][sb * 8], Vg + (size_t)d * NN + j0 + q * 32 + kp * 8);
    }
    __syncthreads();
    f32x4 sacc[2][8] = {};
#pragma unroll
    for (int ks = 0; ks < 2; ++ks) {
      bf16x8 a[2], bfr[8];
#pragma unroll
      for (int mi = 0; mi < 2; ++mi)
        a[mi] = *(const bf16x8*)&Qs[ks][(wid * 32 + mi * 16 + c) * 32 + g * 8];
#pragma unroll
      for (int nj = 0; nj < 8; ++nj)
        bfr[nj] = *(const bf16x8*)&Ks[ks][(nj * 16 + c) * 32 + g * 8];
#pragma unroll
      for (int mi = 0; mi < 2; ++mi)
#pragma unroll
        for (int nj = 0; nj < 8; ++nj)
          sacc[mi][nj] = __builtin_amdgcn_mfma_f32_16x16x32_bf16(a[mi], bfr[nj], sacc[mi][nj], 0, 0, 0);
    }
    float rjv[8], zjv[8];
#pragma unroll
    for (int nj = 0; nj < 8; ++nj) {
      rjv[nj] = ratio_f[b_ * NN + j0 + nj * 16 + c];
      zjv[nj] = Zbuf[(size_t)bh * NN + j0 + nj * 16 + c];
    }
#pragma unroll
    for (int nj = 0; nj < 8; ++nj) {
      int j = j0 + nj * 16 + c;
      int jc = nj >> 1;
      int jl = (nj & 1) * 16 + c;
#pragma unroll
      for (int mi = 0; mi < 2; ++mi)
#pragma unroll
        for (int r = 0; r < 4; ++r) {
          int iL = wid * 32 + mi * 16 + g * 4 + r;
          int i = i0 + iL;
          float s = sacc[mi][nj][r] * 0.125f;
          if (Mg[(size_t)i * NN + j]) s = NEGV;
          s = s * rjv[nj] - zjv[nj];
          Ps[jc][iL * 32 + jl] = f2bf(__expf(s));
        }
    }
    __syncthreads();
#pragma unroll
    for (int ks = 0; ks < 4; ++ks) {
      bf16x8 pa[2], vb[4];
#pragma unroll
      for (int mi = 0; mi < 2; ++mi)
        pa[mi] = *(const bf16x8*)&Ps[ks][(wid * 32 + mi * 16 + c) * 32 + g * 8];
#pragma unroll
      for (int nd = 0; nd < 4; ++nd)
        vb[nd] = *(const bf16x8*)&Vs[ks][(nd * 16 + c) * 32 + g * 8];
#pragma unroll
      for (int mi = 0; mi < 2; ++mi)
#pragma unroll
        for (int nd = 0; nd < 4; ++nd)
          cacc[mi][nd] = __builtin_amdgcn_mfma_f32_16x16x32_bf16(pa[mi], vb[nd], cacc[mi][nd], 0, 0, 0);
    }
  }
#pragma unroll
  for (int mi = 0; mi < 2; ++mi)
#pragma unroll
    for (int nd = 0; nd < 4; ++nd)
#pragma unroll
      for (int r = 0; r < 4; ++r) {
        int i = i0 + wid * 32 + mi * 16 + g * 4 + r;
        int d = nd * 16 + c;
        ctxr[((size_t)(b_ * NN + i)) * CC + h * DD + d] = f2bf(cacc[mi][nd][r]);
      }
}

// ---------- LayerNorm over C=1024 ----------
__global__ __launch_bounds__(256)
void ln_kernel(const float* __restrict__ xbuf, const void* __restrict__ gamma,
               const void* __restrict__ beta, float* __restrict__ out,
               const int* __restrict__ flags) {
  const int row = blockIdx.x;
  const int tid = threadIdx.x;
  const float4 v = ((const float4*)(xbuf + (size_t)row * CC))[tid];
  float s = v.x + v.y + v.z + v.w;
  float s2 = v.x * v.x + v.y * v.y + v.z * v.z + v.w * v.w;
#pragma unroll
  for (int off = 32; off >= 1; off >>= 1) {
    s += __shfl_xor(s, off);
    s2 += __shfl_xor(s2, off);
  }
  __shared__ float red[8];
  const int wid = tid >> 6, lane = tid & 63;
  if (lane == 0) { red[wid] = s; red[4 + wid] = s2; }
  __syncthreads();
  float ts = red[0] + red[1] + red[2] + red[3];
  float ts2 = red[4] + red[5] + red[6] + red[7];
  float mu = ts * (1.f / 1024.f);
  float var = ts2 * (1.f / 1024.f) - mu * mu;
  float rs = rsqrtf(var + 1e-5f);
  const int f32in = flags[0];
  const int cbase = tid * 4;
  float4 o;
  o.x = (v.x - mu) * rs * load_in_f(gamma, cbase + 0, f32in) + load_in_f(beta, cbase + 0, f32in);
  o.y = (v.y - mu) * rs * load_in_f(gamma, cbase + 1, f32in) + load_in_f(beta, cbase + 1, f32in);
  o.z = (v.z - mu) * rs * load_in_f(gamma, cbase + 2, f32in) + load_in_f(beta, cbase + 2, f32in);
  o.w = (v.w - mu) * rs * load_in_f(gamma, cbase + 3, f32in) + load_in_f(beta, cbase + 3, f32in);
  ((float4*)(out + (size_t)row * CC))[tid] = o;
}

// ---------- host ----------
extern "C" void kernel_launch(void* const* d_in, const int* in_sizes, int n_in,
                              void* d_out, int out_size, void* d_ws, size_t ws_size,
                              hipStream_t stream) {
  (void)in_sizes; (void)n_in; (void)out_size; (void)ws_size;
  char* ws = (char*)d_ws;
  size_t off = 0;
  auto alloc = [&](size_t bytes) -> void* {
    void* p = ws + off;
    off += (bytes + 255) & ~(size_t)255;
    return p;
  };
  int*      flags   = (int*)alloc(256);
  float*    Zbuf    = (float*)alloc((size_t)BB * HH * NN * 4);
  float*    ratio_f = (float*)alloc((size_t)BB * NN * 4);
  uint8_t*  maskc   = (uint8_t*)alloc((size_t)BB * NN * NN);
  uint16_t* xq      = (uint16_t*)alloc((size_t)BB * NN * CC * 2);
  uint16_t* xk      = (uint16_t*)alloc((size_t)BB * NN * CC * 2);
  uint16_t* xv      = (uint16_t*)alloc((size_t)BB * NN * CC * 2);
  uint16_t* qb      = (uint16_t*)alloc((size_t)BB * NN * CC * 2);
  uint16_t* kb      = (uint16_t*)alloc((size_t)BB * NN * CC * 2);
  uint16_t* vtb     = (uint16_t*)alloc((size_t)BB * NN * CC * 2);
  uint16_t* Wt      = (uint16_t*)alloc((size_t)4 * CC * CC * 2);
  uint16_t* ctxr    = xq;              // xq dead after Q projection
  float*    xbuf    = (float*)xk;      // xk+xv contiguous 32MB, dead after K/V proj

  detect_kernel<<<1, 64, 0, stream>>>((const uint32_t*)d_in[0], (const uint32_t*)d_in[4], flags);
  conv_bf16<<<4096, 256, 0, stream>>>(d_in[0], xq, BB * NN * CC, flags);
  conv_bf16<<<4096, 256, 0, stream>>>(d_in[1], xk, BB * NN * CC, flags);
  conv_bf16<<<4096, 256, 0, stream>>>(d_in[2], xv, BB * NN * CC, flags);
  conv_ratio<<<32, 256, 0, stream>>>(d_in[3], ratio_f, BB * NN, flags);
  conv_mask<<<4096, 256, 0, stream>>>(d_in[4], maskc, BB * NN * NN, flags);
  transW<<<dim3(32, 32, 4), dim3(32, 8), 0, stream>>>(d_in[5], d_in[6], d_in[7], d_in[8], Wt, flags);

  gemm128<0><<<dim3(64, 8), 256, 0, stream>>>(xq, Wt,               qb,  nullptr, flags);
  gemm128<0><<<dim3(64, 8), 256, 0, stream>>>(xk, Wt + 1 * CC * CC, kb,  nullptr, flags);
  gemm128<1><<<dim3(64, 8), 256, 0, stream>>>(xv, Wt + 2 * CC * CC, vtb, nullptr, flags);

  attn_stats<<<dim3(64, 16), 256, 0, stream>>>(qb, kb, maskc, ratio_f, Zbuf);
  attn_pv<<<dim3(64, 16), 256, 0, stream>>>(qb, kb, vtb, maskc, ratio_f, Zbuf, ctxr);

  gemm128<2><<<dim3(64, 8), 256, 0, stream>>>(ctxr, Wt + 3 * CC * CC, xbuf, d_in[0], flags);
  ln_kernel<<<8192, 256, 0, stream>>>(xbuf, d_in[9], d_in[10], (float*)d_out, flags);
}

// Round 3
// 550.752 us; speedup vs baseline: 1.0593x; 1.0593x over previous
//
#include <hip/hip_runtime.h>
#include <hip/hip_bf16.h>
#include <stdint.h>

#define BB 4
#define NN 2048
#define CC 1024
#define HH 16
#define DD 64

typedef __attribute__((ext_vector_type(8))) short bf16x8;
typedef __attribute__((ext_vector_type(4))) float f32x4;

#define LOG2E 1.44269504088896f

// ---------- small helpers ----------
__device__ __forceinline__ unsigned short f2bf(float x) {
  uint32_t u = __float_as_uint(x);
  uint32_t r = (u + 0x7FFFu + ((u >> 16) & 1u)) >> 16;   // RNE
  return (unsigned short)r;
}
__device__ __forceinline__ float bf2f(unsigned short v) {
  return __uint_as_float(((uint32_t)v) << 16);
}
__device__ __forceinline__ float load_in_f(const void* p, size_t idx, int f32in) {
  if (f32in) return ((const float*)p)[idx];
  return bf2f(((const uint16_t*)p)[idx]);
}
// async global->LDS, 16B per lane; lds ptr must be the wave-uniform base
__device__ __forceinline__ void gload16(uint16_t* lds_base, const uint16_t* gsrc) {
  __builtin_amdgcn_global_load_lds(
      (const __attribute__((address_space(1))) uint32_t*)(const void*)gsrc,
      (__attribute__((address_space(3))) uint32_t*)(void*)lds_base,
      16, 0, 0);
}

// ---------- dtype detection ----------
__global__ void detect_kernel(const uint32_t* __restrict__ q,
                              const uint32_t* __restrict__ m,
                              int* __restrict__ flags) {
  if (threadIdx.x == 0 && blockIdx.x == 0) {
    int sane = 0;
    for (int i = 0; i < 128; ++i) {
      uint32_t w = q[i];
      int e0 = (int)((w >> 7) & 0xFFu);
      int e1 = (int)((w >> 23) & 0xFFu);
      sane += (e0 >= 0x70 && e0 <= 0x8F) ? 1 : 0;
      sane += (e1 >= 0x70 && e1 <= 0x8F) ? 1 : 0;
    }
    flags[0] = (sane >= 208) ? 0 : 1;   // 1 => fp32 inputs
    int allsmall = 1;
    for (int i = 0; i < 16; ++i) if (m[i] > 1u) allsmall = 0;
    flags[1] = allsmall;                 // 1 => mask is int32
  }
}

// ---------- conversions (q,k,v in one launch via z) ----------
__global__ void conv_bf16_3(const void* __restrict__ s0, const void* __restrict__ s1,
                            const void* __restrict__ s2,
                            uint16_t* __restrict__ d0, uint16_t* __restrict__ d1,
                            uint16_t* __restrict__ d2,
                            int n, const int* __restrict__ flags) {
  const int f32in = flags[0];
  const void* src = (blockIdx.z == 0) ? s0 : (blockIdx.z == 1) ? s1 : s2;
  uint16_t* dst = (blockIdx.z == 0) ? d0 : (blockIdx.z == 1) ? d1 : d2;
  int idx = blockIdx.x * blockDim.x + threadIdx.x;
  const int total = n >> 2;
  const int stride = gridDim.x * blockDim.x;
  if (f32in) {
    const float4* s = (const float4*)src;
    for (; idx < total; idx += stride) {
      float4 v = s[idx];
      ushort4 o;
      o.x = f2bf(v.x); o.y = f2bf(v.y); o.z = f2bf(v.z); o.w = f2bf(v.w);
      ((ushort4*)dst)[idx] = o;
    }
  } else {
    const ushort4* s = (const ushort4*)src;
    for (; idx < total; idx += stride) ((ushort4*)dst)[idx] = s[idx];
  }
}

__global__ void conv_ratio(const void* __restrict__ src, float* __restrict__ dst,
                           int n, const int* __restrict__ flags) {
  const int f32in = flags[0];
  int idx = blockIdx.x * blockDim.x + threadIdx.x;
  const int stride = gridDim.x * blockDim.x;
  for (; idx < n; idx += stride) dst[idx] = load_in_f(src, idx, f32in);
}

// ---------- mask -> bit pack.  bit j of word (b,i,j>>5): mask[b][i][j] ----------
__global__ void conv_maskbits(const void* __restrict__ src, uint32_t* __restrict__ dst,
                              int n, const int* __restrict__ flags) {
  const int isint = flags[1];
  const int gw = (blockIdx.x * blockDim.x + threadIdx.x) >> 6;
  const int lane = threadIdx.x & 63;
  const int nw = (gridDim.x * blockDim.x) >> 6;
  const int totalw = n >> 6;            // 64 elements per wave-iter
  for (int w = gw; w < totalw; w += nw) {
    int e = w * 64 + lane;
    bool m;
    if (isint) m = (((const int*)src)[e] != 0);
    else       m = (((const uint8_t*)src)[e] != 0);
    unsigned long long bal = __ballot(m);
    if (lane == 0) ((unsigned long long*)dst)[w] = bal;
  }
}

// ---------- W transpose + bf16 convert: Wt[n][k] = W[k][n] ----------
__global__ __launch_bounds__(256)
void transW(const void* w0, const void* w1, const void* w2, const void* w3,
            uint16_t* __restrict__ wt, const int* __restrict__ flags) {
  const int f32in = flags[0];
  const void* src = (blockIdx.z == 0) ? w0 : (blockIdx.z == 1) ? w1
                   : (blockIdx.z == 2) ? w2 : w3;
  uint16_t* dst = wt + (size_t)blockIdx.z * CC * CC;
  __shared__ float t[32][33];
  const int tx = threadIdx.x, ty = threadIdx.y;
  const int n0 = blockIdx.x * 32, k0 = blockIdx.y * 32;
#pragma unroll
  for (int r = 0; r < 4; ++r) {
    int k = k0 + ty + r * 8;
    t[ty + r * 8][tx] = load_in_f(src, (size_t)k * CC + n0 + tx, f32in);
  }
  __syncthreads();
#pragma unroll
  for (int r = 0; r < 4; ++r) {
    int n = n0 + ty + r * 8;
    dst[(size_t)n * CC + k0 + tx] = f2bf(t[tx][ty + r * 8]);
  }
}

// ---------- 128x128x(BK=32) bf16 MFMA GEMM ----------
// LDS tiles XOR-swizzled: 16B granule g stored at g^(row&3) (source pre-swizzle,
// linear global_load_lds dest), reads use g^(row&3).
template <int MODE>
__global__ __launch_bounds__(256, 2)
void gemm128(const uint16_t* __restrict__ A, const uint16_t* __restrict__ Bt,
             void* __restrict__ out, const void* __restrict__ resid,
             const int* __restrict__ flags) {
  __shared__ uint16_t As[128 * 32];
  __shared__ uint16_t Bs[128 * 32];
  const int tid = threadIdx.x;
  const int wid = tid >> 6, lane = tid & 63;
  const int g = lane >> 4, c = lane & 15;
  const int m0 = blockIdx.x * 128, n0 = blockIdx.y * 128;
  const int wr = wid >> 1, wc = wid & 1;
  f32x4 acc[4][4] = {};
  for (int k0 = 0; k0 < 1024; k0 += 32) {
    __syncthreads();
#pragma unroll
    for (int is = 0; is < 2; ++is) {
      int sb = is * 256 + wid * 64;
      int s = sb + lane;
      int r = s >> 2, kp = s & 3;
      int kps = kp ^ (r & 3);
      gload16(&As[sb * 8], A + (size_t)(m0 + r) * 1024 + k0 + kps * 8);
      gload16(&Bs[sb * 8], Bt + (size_t)(n0 + r) * 1024 + k0 + kps * 8);
    }
    __syncthreads();
    bf16x8 a[4], b[4];
#pragma unroll
    for (int mi = 0; mi < 4; ++mi) {
      int row = wr * 64 + mi * 16 + c;
      a[mi] = *(const bf16x8*)&As[row * 32 + (g ^ (row & 3)) * 8];
    }
#pragma unroll
    for (int ni = 0; ni < 4; ++ni) {
      int row = wc * 64 + ni * 16 + c;
      b[ni] = *(const bf16x8*)&Bs[row * 32 + (g ^ (row & 3)) * 8];
    }
#pragma unroll
    for (int mi = 0; mi < 4; ++mi)
#pragma unroll
      for (int ni = 0; ni < 4; ++ni)
        acc[mi][ni] = __builtin_amdgcn_mfma_f32_16x16x32_bf16(a[mi], b[ni], acc[mi][ni], 0, 0, 0);
  }
  const int f32in = flags[0];
#pragma unroll
  for (int mi = 0; mi < 4; ++mi)
#pragma unroll
    for (int ni = 0; ni < 4; ++ni)
#pragma unroll
      for (int r = 0; r < 4; ++r) {
        int mrow = m0 + wr * 64 + mi * 16 + g * 4 + r;
        int ncol = n0 + wc * 64 + ni * 16 + c;
        float v = acc[mi][ni][r];
        if (MODE == 0) {
          int b_ = mrow >> 11, i = mrow & 2047, h = ncol >> 6, d = ncol & 63;
          ((uint16_t*)out)[((size_t)(b_ * 16 + h) * 2048 + i) * 64 + d] = f2bf(v);
        } else if (MODE == 1) {
          int b_ = mrow >> 11, i = mrow & 2047, h = ncol >> 6, d = ncol & 63;
          ((uint16_t*)out)[((size_t)(b_ * 16 + h) * 64 + d) * 2048 + i] = f2bf(v);
        } else {
          size_t idx = (size_t)mrow * 1024 + ncol;
          ((float*)out)[idx] = v + load_in_f(resid, idx, f32in);
        }
      }
}

// ---------- pass 1: column stats, no max-tracking: Z_j = log2(sum_i 2^(s*r*l2e)) ----------
__global__ __launch_bounds__(256, 2)
void attn_stats(const uint16_t* __restrict__ qb, const uint16_t* __restrict__ kb,
                const uint32_t* __restrict__ mbits, const float* __restrict__ ratio_f,
                float* __restrict__ Zbuf) {
  __shared__ uint16_t Ks[2][128 * 32];
  __shared__ uint16_t Qs[2][128 * 32];
  __shared__ float redL[4][128];
  const int tid = threadIdx.x, wid = tid >> 6, lane = tid & 63;
  const int g = lane >> 4, c = lane & 15;
  const int bh = blockIdx.x, b_ = bh >> 4;
  const int j0 = blockIdx.y * 128;
  const uint16_t* Kg = kb + (size_t)bh * NN * DD + (size_t)j0 * DD;
  const uint16_t* Qg = qb + (size_t)bh * NN * DD;
  const uint32_t* Mrow = mbits + (size_t)b_ * NN * 64 + (j0 >> 5);
#pragma unroll
  for (int hf = 0; hf < 2; ++hf)
#pragma unroll
    for (int is = 0; is < 2; ++is) {
      int sb = is * 256 + wid * 64;
      int s = sb + lane;
      int r = s >> 2, kp = s & 3;
      int kps = kp ^ (r & 3);
      gload16(&Ks[hf][sb * 8], Kg + (size_t)r * 64 + hf * 32 + kps * 8);
    }
  float rjl2[8], negr[8], l_[8];
#pragma unroll
  for (int nj = 0; nj < 8; ++nj) {
    float r = ratio_f[b_ * NN + j0 + nj * 16 + c];
    rjl2[nj] = r * 0.125f * LOG2E;
    negr[nj] = r * (-1e9f) * LOG2E;
    l_[nj] = 0.f;
  }
  for (int i0 = 0; i0 < NN; i0 += 128) {
    __syncthreads();
#pragma unroll
    for (int hf = 0; hf < 2; ++hf)
#pragma unroll
      for (int is = 0; is < 2; ++is) {
        int sb = is * 256 + wid * 64;
        int s = sb + lane;
        int r = s >> 2, kp = s & 3;
        int kps = kp ^ (r & 3);
        gload16(&Qs[hf][sb * 8], Qg + (size_t)(i0 + r) * 64 + hf * 32 + kps * 8);
      }
    __syncthreads();
    f32x4 sacc[2][8] = {};
#pragma unroll
    for (int ks = 0; ks < 2; ++ks) {
      bf16x8 a[2], bfr[8];
#pragma unroll
      for (int mi = 0; mi < 2; ++mi) {
        int row = wid * 32 + mi * 16 + c;
        a[mi] = *(const bf16x8*)&Qs[ks][row * 32 + (g ^ (row & 3)) * 8];
      }
#pragma unroll
      for (int nj = 0; nj < 8; ++nj) {
        int row = nj * 16 + c;
        bfr[nj] = *(const bf16x8*)&Ks[ks][row * 32 + (g ^ (row & 3)) * 8];
      }
#pragma unroll
      for (int mi = 0; mi < 2; ++mi)
#pragma unroll
        for (int nj = 0; nj < 8; ++nj)
          sacc[mi][nj] = __builtin_amdgcn_mfma_f32_16x16x32_bf16(a[mi], bfr[nj], sacc[mi][nj], 0, 0, 0);
    }
#pragma unroll
    for (int mi = 0; mi < 2; ++mi)
#pragma unroll
      for (int r = 0; r < 4; ++r) {
        int i = i0 + wid * 32 + mi * 16 + g * 4 + r;
        const uint4 mw = *(const uint4*)(Mrow + (size_t)i * 64);
#pragma unroll
        for (int nj = 0; nj < 8; ++nj) {
          uint32_t w = (nj < 2) ? mw.x : (nj < 4) ? mw.y : (nj < 6) ? mw.z : mw.w;
          bool bit = (w >> ((nj & 1) * 16 + c)) & 1u;
          float se = bit ? negr[nj] : sacc[mi][nj][r] * rjl2[nj];
          l_[nj] += exp2f(se);
        }
      }
  }
#pragma unroll
  for (int nj = 0; nj < 8; ++nj) {
    float l = l_[nj];
    l += __shfl_xor(l, 16);
    l += __shfl_xor(l, 32);
    if (g == 0) redL[wid][nj * 16 + c] = l;
  }
  __syncthreads();
  if (tid < 128) {
    float L = redL[0][tid] + redL[1][tid] + redL[2][tid] + redL[3][tid];
    Zbuf[(size_t)bh * NN + j0 + tid] = log2f(L);
  }
}

// ---------- pass 2: weights + PV -> ctx [B,N,H*D] bf16 ----------
__global__ __launch_bounds__(256, 2)
void attn_pv(const uint16_t* __restrict__ qb, const uint16_t* __restrict__ kb,
             const uint16_t* __restrict__ vt, const uint32_t* __restrict__ mbits,
             const float* __restrict__ ratio_f, const float* __restrict__ Zbuf,
             uint16_t* __restrict__ ctxr) {
  __shared__ uint16_t Qs[2][128 * 32];
  __shared__ uint16_t Ks[2][128 * 32];
  __shared__ uint16_t Vs[4][64 * 32];
  __shared__ uint16_t Ps[4][128 * 32];
  const int tid = threadIdx.x, wid = tid >> 6, lane = tid & 63;
  const int g = lane >> 4, c = lane & 15;
  const int bh = blockIdx.x, b_ = bh >> 4, h = bh & 15;
  const int i0 = blockIdx.y * 128;
  const uint16_t* Qg = qb + (size_t)bh * NN * DD;
  const uint16_t* Kg = kb + (size_t)bh * NN * DD;
  const uint16_t* Vg = vt + (size_t)bh * DD * NN;
  const uint32_t* Mb = mbits + (size_t)b_ * NN * 64;
#pragma unroll
  for (int hf = 0; hf < 2; ++hf)
#pragma unroll
    for (int is = 0; is < 2; ++is) {
      int sb = is * 256 + wid * 64;
      int s = sb + lane;
      int r = s >> 2, kp = s & 3;
      int kps = kp ^ (r & 3);
      gload16(&Qs[hf][sb * 8], Qg + (size_t)(i0 + r) * 64 + hf * 32 + kps * 8);
    }
  f32x4 cacc[2][4] = {};
  for (int j0 = 0; j0 < NN; j0 += 128) {
    __syncthreads();
#pragma unroll
    for (int hf = 0; hf < 2; ++hf)
#pragma unroll
      for (int is = 0; is < 2; ++is) {
        int sb = is * 256 + wid * 64;
        int s = sb + lane;
        int r = s >> 2, kp = s & 3;
        int kps = kp ^ (r & 3);
        gload16(&Ks[hf][sb * 8], Kg + (size_t)(j0 + r) * 64 + hf * 32 + kps * 8);
      }
#pragma unroll
    for (int vq = 0; vq < 4; ++vq) {
      int sb = wid * 64;
      int s = sb + lane;
      int d = s >> 2, kp = s & 3;
      int kps = kp ^ (d & 3);
      gload16(&Vs[vq][sb * 8], Vg + (size_t)d * NN + j0 + vq * 32 + kps * 8);
    }
    __syncthreads();
    f32x4 sacc[2][8] = {};
#pragma unroll
    for (int ks = 0; ks < 2; ++ks) {
      bf16x8 a[2], bfr[8];
#pragma unroll
      for (int mi = 0; mi < 2; ++mi) {
        int row = wid * 32 + mi * 16 + c;
        a[mi] = *(const bf16x8*)&Qs[ks][row * 32 + (g ^ (row & 3)) * 8];
      }
#pragma unroll
      for (int nj = 0; nj < 8; ++nj) {
        int row = nj * 16 + c;
        bfr[nj] = *(const bf16x8*)&Ks[ks][row * 32 + (g ^ (row & 3)) * 8];
      }
#pragma unroll
      for (int mi = 0; mi < 2; ++mi)
#pragma unroll
        for (int nj = 0; nj < 8; ++nj)
          sacc[mi][nj] = __builtin_amdgcn_mfma_f32_16x16x32_bf16(a[mi], bfr[nj], sacc[mi][nj], 0, 0, 0);
    }
    float rjl2[8], negr[8], zl2[8];
#pragma unroll
    for (int nj = 0; nj < 8; ++nj) {
      float r = ratio_f[b_ * NN + j0 + nj * 16 + c];
      rjl2[nj] = r * 0.125f * LOG2E;
      negr[nj] = r * (-1e9f) * LOG2E;
      zl2[nj] = Zbuf[(size_t)bh * NN + j0 + nj * 16 + c];
    }
#pragma unroll
    for (int mi = 0; mi < 2; ++mi)
#pragma unroll
      for (int r = 0; r < 4; ++r) {
        int iL = wid * 32 + mi * 16 + g * 4 + r;
        int i = i0 + iL;
        const uint4 mw = *(const uint4*)(Mb + (size_t)i * 64 + (j0 >> 5));
#pragma unroll
        for (int nj = 0; nj < 8; ++nj) {
          uint32_t w = (nj < 2) ? mw.x : (nj < 4) ? mw.y : (nj < 6) ? mw.z : mw.w;
          bool bit = (w >> ((nj & 1) * 16 + c)) & 1u;
          float se = bit ? negr[nj] : sacc[mi][nj][r] * rjl2[nj];
          float p = exp2f(se - zl2[nj]);
          int jl = (nj & 1) * 16 + c;
          int jc = nj >> 1;
          Ps[jc][iL * 32 + (((jl >> 3) ^ (iL & 3)) * 8) + (jl & 7)] = f2bf(p);
        }
      }
    __syncthreads();
#pragma unroll
    for (int ks = 0; ks < 4; ++ks) {
      bf16x8 pa[2], vb[4];
#pragma unroll
      for (int mi = 0; mi < 2; ++mi) {
        int row = wid * 32 + mi * 16 + c;
        pa[mi] = *(const bf16x8*)&Ps[ks][row * 32 + (g ^ (row & 3)) * 8];
      }
#pragma unroll
      for (int nd = 0; nd < 4; ++nd) {
        int row = nd * 16 + c;
        vb[nd] = *(const bf16x8*)&Vs[ks][row * 32 + (g ^ (row & 3)) * 8];
      }
#pragma unroll
      for (int mi = 0; mi < 2; ++mi)
#pragma unroll
        for (int nd = 0; nd < 4; ++nd)
          cacc[mi][nd] = __builtin_amdgcn_mfma_f32_16x16x32_bf16(pa[mi], vb[nd], cacc[mi][nd], 0, 0, 0);
    }
  }
#pragma unroll
  for (int mi = 0; mi < 2; ++mi)
#pragma unroll
    for (int nd = 0; nd < 4; ++nd)
#pragma unroll
      for (int r = 0; r < 4; ++r) {
        int i = i0 + wid * 32 + mi * 16 + g * 4 + r;
        int d = nd * 16 + c;
        ctxr[((size_t)(b_ * NN + i)) * CC + h * DD + d] = f2bf(cacc[mi][nd][r]);
      }
}

// ---------- LayerNorm over C=1024 ----------
__global__ __launch_bounds__(256)
void ln_kernel(const float* __restrict__ xbuf, const void* __restrict__ gamma,
               const void* __restrict__ beta, float* __restrict__ out,
               const int* __restrict__ flags) {
  const int row = blockIdx.x;
  const int tid = threadIdx.x;
  const float4 v = ((const float4*)(xbuf + (size_t)row * CC))[tid];
  float s = v.x + v.y + v.z + v.w;
  float s2 = v.x * v.x + v.y * v.y + v.z * v.z + v.w * v.w;
#pragma unroll
  for (int off = 32; off >= 1; off >>= 1) {
    s += __shfl_xor(s, off);
    s2 += __shfl_xor(s2, off);
  }
  __shared__ float red[8];
  const int wid = tid >> 6, lane = tid & 63;
  if (lane == 0) { red[wid] = s; red[4 + wid] = s2; }
  __syncthreads();
  float ts = red[0] + red[1] + red[2] + red[3];
  float ts2 = red[4] + red[5] + red[6] + red[7];
  float mu = ts * (1.f / 1024.f);
  float var = ts2 * (1.f / 1024.f) - mu * mu;
  float rs = rsqrtf(var + 1e-5f);
  const int f32in = flags[0];
  const int cbase = tid * 4;
  float4 o;
  o.x = (v.x - mu) * rs * load_in_f(gamma, cbase + 0, f32in) + load_in_f(beta, cbase + 0, f32in);
  o.y = (v.y - mu) * rs * load_in_f(gamma, cbase + 1, f32in) + load_in_f(beta, cbase + 1, f32in);
  o.z = (v.z - mu) * rs * load_in_f(gamma, cbase + 2, f32in) + load_in_f(beta, cbase + 2, f32in);
  o.w = (v.w - mu) * rs * load_in_f(gamma, cbase + 3, f32in) + load_in_f(beta, cbase + 3, f32in);
  ((float4*)(out + (size_t)row * CC))[tid] = o;
}

// ---------- host ----------
extern "C" void kernel_launch(void* const* d_in, const int* in_sizes, int n_in,
                              void* d_out, int out_size, void* d_ws, size_t ws_size,
                              hipStream_t stream) {
  (void)in_sizes; (void)n_in; (void)out_size; (void)ws_size;
  char* ws = (char*)d_ws;
  size_t off = 0;
  auto alloc = [&](size_t bytes) -> void* {
    void* p = ws + off;
    off += (bytes + 255) & ~(size_t)255;
    return p;
  };
  int*      flags   = (int*)alloc(256);
  float*    Zbuf    = (float*)alloc((size_t)BB * HH * NN * 4);
  float*    ratio_f = (float*)alloc((size_t)BB * NN * 4);
  uint32_t* mbits   = (uint32_t*)alloc((size_t)BB * NN * 64 * 4);   // 2 MB bit mask
  uint16_t* xq      = (uint16_t*)alloc((size_t)BB * NN * CC * 2);
  uint16_t* xk      = (uint16_t*)alloc((size_t)BB * NN * CC * 2);
  uint16_t* xv      = (uint16_t*)alloc((size_t)BB * NN * CC * 2);
  uint16_t* qb      = (uint16_t*)alloc((size_t)BB * NN * CC * 2);
  uint16_t* kb      = (uint16_t*)alloc((size_t)BB * NN * CC * 2);
  uint16_t* vtb     = (uint16_t*)alloc((size_t)BB * NN * CC * 2);
  uint16_t* Wt      = (uint16_t*)alloc((size_t)4 * CC * CC * 2);
  uint16_t* ctxr    = xq;              // xq dead after Q projection
  float*    xbuf    = (float*)xk;      // xk+xv contiguous 32MB, dead after K/V proj

  detect_kernel<<<1, 64, 0, stream>>>((const uint32_t*)d_in[0], (const uint32_t*)d_in[4], flags);
  conv_bf16_3<<<dim3(2048, 1, 3), 256, 0, stream>>>(d_in[0], d_in[1], d_in[2],
                                                    xq, xk, xv, BB * NN * CC, flags);
  conv_ratio<<<32, 256, 0, stream>>>(d_in[3], ratio_f, BB * NN, flags);
  conv_maskbits<<<2048, 256, 0, stream>>>(d_in[4], mbits, BB * NN * NN, flags);
  transW<<<dim3(32, 32, 4), dim3(32, 8), 0, stream>>>(d_in[5], d_in[6], d_in[7], d_in[8], Wt, flags);

  gemm128<0><<<dim3(64, 8), 256, 0, stream>>>(xq, Wt,               qb,  nullptr, flags);
  gemm128<0><<<dim3(64, 8), 256, 0, stream>>>(xk, Wt + 1 * CC * CC, kb,  nullptr, flags);
  gemm128<1><<<dim3(64, 8), 256, 0, stream>>>(xv, Wt + 2 * CC * CC, vtb, nullptr, flags);

  attn_stats<<<dim3(64, 16), 256, 0, stream>>>(qb, kb, mbits, ratio_f, Zbuf);
  attn_pv<<<dim3(64, 16), 256, 0, stream>>>(qb, kb, vtb, mbits, ratio_f, Zbuf, ctxr);

  gemm128<2><<<dim3(64, 8), 256, 0, stream>>>(ctxr, Wt + 3 * CC * CC, xbuf, d_in[0], flags);
  ln_kernel<<<8192, 256, 0, stream>>>(xbuf, d_in[9], d_in[10], (float*)d_out, flags);
}

// Round 4
// 508.215 us; speedup vs baseline: 1.1480x; 1.0837x over previous
//
#include <hip/hip_runtime.h>
#include <hip/hip_bf16.h>
#include <stdint.h>

#define BB 4
#define NN 2048
#define CC 1024
#define HH 16
#define DD 64

typedef __attribute__((ext_vector_type(8))) short bf16x8;
typedef __attribute__((ext_vector_type(4))) float f32x4;

#define LOG2E 1.44269504088896f

// ---------- small helpers ----------
__device__ __forceinline__ unsigned short f2bf(float x) {
  uint32_t u = __float_as_uint(x);
  uint32_t r = (u + 0x7FFFu + ((u >> 16) & 1u)) >> 16;   // RNE
  return (unsigned short)r;
}
__device__ __forceinline__ float bf2f(unsigned short v) {
  return __uint_as_float(((uint32_t)v) << 16);
}
__device__ __forceinline__ float load_in_f(const void* p, size_t idx, int f32in) {
  if (f32in) return ((const float*)p)[idx];
  return bf2f(((const uint16_t*)p)[idx]);
}
// async global->LDS, 16B per lane; lds ptr must be the wave-uniform base
__device__ __forceinline__ void gload16(uint16_t* lds_base, const uint16_t* gsrc) {
  __builtin_amdgcn_global_load_lds(
      (const __attribute__((address_space(1))) uint32_t*)(const void*)gsrc,
      (__attribute__((address_space(3))) uint32_t*)(void*)lds_base,
      16, 0, 0);
}

// ---------- dtype detection ----------
__global__ void detect_kernel(const uint32_t* __restrict__ q,
                              const uint32_t* __restrict__ m,
                              int* __restrict__ flags) {
  if (threadIdx.x == 0 && blockIdx.x == 0) {
    int sane = 0;
    for (int i = 0; i < 128; ++i) {
      uint32_t w = q[i];
      int e0 = (int)((w >> 7) & 0xFFu);
      int e1 = (int)((w >> 23) & 0xFFu);
      sane += (e0 >= 0x70 && e0 <= 0x8F) ? 1 : 0;
      sane += (e1 >= 0x70 && e1 <= 0x8F) ? 1 : 0;
    }
    flags[0] = (sane >= 208) ? 0 : 1;   // 1 => fp32 inputs
    int allsmall = 1;
    for (int i = 0; i < 16; ++i) if (m[i] > 1u) allsmall = 0;
    flags[1] = allsmall;                 // 1 => mask is int32
  }
}

// ---------- conversions (q,k,v in one launch via z) ----------
__global__ void conv_bf16_3(const void* __restrict__ s0, const void* __restrict__ s1,
                            const void* __restrict__ s2,
                            uint16_t* __restrict__ d0, uint16_t* __restrict__ d1,
                            uint16_t* __restrict__ d2,
                            int n, const int* __restrict__ flags) {
  const int f32in = flags[0];
  const void* src = (blockIdx.z == 0) ? s0 : (blockIdx.z == 1) ? s1 : s2;
  uint16_t* dst = (blockIdx.z == 0) ? d0 : (blockIdx.z == 1) ? d1 : d2;
  int idx = blockIdx.x * blockDim.x + threadIdx.x;
  const int total = n >> 2;
  const int stride = gridDim.x * blockDim.x;
  if (f32in) {
    const float4* s = (const float4*)src;
    for (; idx < total; idx += stride) {
      float4 v = s[idx];
      ushort4 o;
      o.x = f2bf(v.x); o.y = f2bf(v.y); o.z = f2bf(v.z); o.w = f2bf(v.w);
      ((ushort4*)dst)[idx] = o;
    }
  } else {
    const ushort4* s = (const ushort4*)src;
    for (; idx < total; idx += stride) ((ushort4*)dst)[idx] = s[idx];
  }
}

__global__ void conv_ratio(const void* __restrict__ src, float* __restrict__ dst,
                           int n, const int* __restrict__ flags) {
  const int f32in = flags[0];
  int idx = blockIdx.x * blockDim.x + threadIdx.x;
  const int stride = gridDim.x * blockDim.x;
  for (; idx < n; idx += stride) dst[idx] = load_in_f(src, idx, f32in);
}

// ---------- mask -> bit pack.  bit j of word (b,i,j>>5): mask[b][i][j] ----------
__global__ void conv_maskbits(const void* __restrict__ src, uint32_t* __restrict__ dst,
                              int n, const int* __restrict__ flags) {
  const int isint = flags[1];
  const int gw = (blockIdx.x * blockDim.x + threadIdx.x) >> 6;
  const int lane = threadIdx.x & 63;
  const int nw = (gridDim.x * blockDim.x) >> 6;
  const int totalw = n >> 6;            // 64 elements per wave-iter
  for (int w = gw; w < totalw; w += nw) {
    int e = w * 64 + lane;
    bool m;
    if (isint) m = (((const int*)src)[e] != 0);
    else       m = (((const uint8_t*)src)[e] != 0);
    unsigned long long bal = __ballot(m);
    if (lane == 0) ((unsigned long long*)dst)[w] = bal;
  }
}

// ---------- W transpose + bf16 convert: Wt[n][k] = W[k][n] ----------
__global__ __launch_bounds__(256)
void transW(const void* w0, const void* w1, const void* w2, const void* w3,
            uint16_t* __restrict__ wt, const int* __restrict__ flags) {
  const int f32in = flags[0];
  const void* src = (blockIdx.z == 0) ? w0 : (blockIdx.z == 1) ? w1
                   : (blockIdx.z == 2) ? w2 : w3;
  uint16_t* dst = wt + (size_t)blockIdx.z * CC * CC;
  __shared__ float t[32][33];
  const int tx = threadIdx.x, ty = threadIdx.y;
  const int n0 = blockIdx.x * 32, k0 = blockIdx.y * 32;
#pragma unroll
  for (int r = 0; r < 4; ++r) {
    int k = k0 + ty + r * 8;
    t[ty + r * 8][tx] = load_in_f(src, (size_t)k * CC + n0 + tx, f32in);
  }
  __syncthreads();
#pragma unroll
  for (int r = 0; r < 4; ++r) {
    int n = n0 + ty + r * 8;
    dst[(size_t)n * CC + k0 + tx] = f2bf(t[tx][ty + r * 8]);
  }
}

// ---------- 128x128x(BK=32) bf16 MFMA GEMM ----------
// LDS tiles XOR-swizzled with key (row>>1)&3 on 16B granules (2-way-free reads):
// source pre-swizzle for linear global_load_lds dest; reads use g^((row>>1)&3).
template <int MODE>
__global__ __launch_bounds__(256, 2)
void gemm128(const uint16_t* __restrict__ A, const uint16_t* __restrict__ Bt,
             void* __restrict__ out, const void* __restrict__ resid,
             const int* __restrict__ flags) {
  __shared__ uint16_t As[128 * 32];
  __shared__ uint16_t Bs[128 * 32];
  const int tid = threadIdx.x;
  const int wid = tid >> 6, lane = tid & 63;
  const int g = lane >> 4, c = lane & 15;
  const int m0 = blockIdx.x * 128, n0 = blockIdx.y * 128;
  const int wr = wid >> 1, wc = wid & 1;
  f32x4 acc[4][4] = {};
  for (int k0 = 0; k0 < 1024; k0 += 32) {
    __syncthreads();
#pragma unroll
    for (int is = 0; is < 2; ++is) {
      int sb = is * 256 + wid * 64;
      int s = sb + lane;
      int r = s >> 2, kp = s & 3;
      int kps = kp ^ ((r >> 1) & 3);
      gload16(&As[sb * 8], A + (size_t)(m0 + r) * 1024 + k0 + kps * 8);
      gload16(&Bs[sb * 8], Bt + (size_t)(n0 + r) * 1024 + k0 + kps * 8);
    }
    __syncthreads();
    bf16x8 a[4], b[4];
#pragma unroll
    for (int mi = 0; mi < 4; ++mi) {
      int row = wr * 64 + mi * 16 + c;
      a[mi] = *(const bf16x8*)&As[row * 32 + (g ^ ((row >> 1) & 3)) * 8];
    }
#pragma unroll
    for (int ni = 0; ni < 4; ++ni) {
      int row = wc * 64 + ni * 16 + c;
      b[ni] = *(const bf16x8*)&Bs[row * 32 + (g ^ ((row >> 1) & 3)) * 8];
    }
#pragma unroll
    for (int mi = 0; mi < 4; ++mi)
#pragma unroll
      for (int ni = 0; ni < 4; ++ni)
        acc[mi][ni] = __builtin_amdgcn_mfma_f32_16x16x32_bf16(a[mi], b[ni], acc[mi][ni], 0, 0, 0);
  }
  const int f32in = flags[0];
#pragma unroll
  for (int mi = 0; mi < 4; ++mi)
#pragma unroll
    for (int ni = 0; ni < 4; ++ni)
#pragma unroll
      for (int r = 0; r < 4; ++r) {
        int mrow = m0 + wr * 64 + mi * 16 + g * 4 + r;
        int ncol = n0 + wc * 64 + ni * 16 + c;
        float v = acc[mi][ni][r];
        if (MODE == 0) {
          int b_ = mrow >> 11, i = mrow & 2047, h = ncol >> 6, d = ncol & 63;
          ((uint16_t*)out)[((size_t)(b_ * 16 + h) * 2048 + i) * 64 + d] = f2bf(v);
        } else if (MODE == 1) {
          int b_ = mrow >> 11, i = mrow & 2047, h = ncol >> 6, d = ncol & 63;
          ((uint16_t*)out)[((size_t)(b_ * 16 + h) * 64 + d) * 2048 + i] = f2bf(v);
        } else {
          size_t idx = (size_t)mrow * 1024 + ncol;
          ((float*)out)[idx] = v + load_in_f(resid, idx, f32in);
        }
      }
}

// ---------- pass 1: column stats: L_j = sum_i 2^(s*r*l2e); writes RZ=(rjl2, log2 L) ----------
__global__ __launch_bounds__(256, 2)
void attn_stats(const uint16_t* __restrict__ qb, const uint16_t* __restrict__ kb,
                const uint32_t* __restrict__ mbits, const float* __restrict__ ratio_f,
                float2* __restrict__ RZ) {
  __shared__ uint16_t Ks[2][128 * 32];
  __shared__ uint16_t Qs[2][128 * 32];
  __shared__ float redL[4][128];
  const int tid = threadIdx.x, wid = tid >> 6, lane = tid & 63;
  const int g = lane >> 4, c = lane & 15;
  const int bh = blockIdx.x, b_ = bh >> 4;
  const int j0 = blockIdx.y * 128;
  const uint16_t* Kg = kb + (size_t)bh * NN * DD + (size_t)j0 * DD;
  const uint16_t* Qg = qb + (size_t)bh * NN * DD;
  const uint32_t* Mrow = mbits + (size_t)b_ * NN * 64 + (j0 >> 5);
#pragma unroll
  for (int hf = 0; hf < 2; ++hf)
#pragma unroll
    for (int is = 0; is < 2; ++is) {
      int sb = is * 256 + wid * 64;
      int s = sb + lane;
      int r = s >> 2, kp = s & 3;
      int kps = kp ^ ((r >> 1) & 3);
      gload16(&Ks[hf][sb * 8], Kg + (size_t)r * 64 + hf * 32 + kps * 8);
    }
  float rjl2[8], negr[8], l_[8];
#pragma unroll
  for (int nj = 0; nj < 8; ++nj) {
    float r = ratio_f[b_ * NN + j0 + nj * 16 + c];
    rjl2[nj] = r * 0.125f * LOG2E;
    negr[nj] = r * (-1e9f) * LOG2E;
    l_[nj] = 0.f;
  }
  for (int i0 = 0; i0 < NN; i0 += 128) {
    __syncthreads();
#pragma unroll
    for (int hf = 0; hf < 2; ++hf)
#pragma unroll
      for (int is = 0; is < 2; ++is) {
        int sb = is * 256 + wid * 64;
        int s = sb + lane;
        int r = s >> 2, kp = s & 3;
        int kps = kp ^ ((r >> 1) & 3);
        gload16(&Qs[hf][sb * 8], Qg + (size_t)(i0 + r) * 64 + hf * 32 + kps * 8);
      }
    __syncthreads();
    f32x4 sacc[2][8] = {};
#pragma unroll
    for (int ks = 0; ks < 2; ++ks) {
      bf16x8 a[2], bfr[8];
#pragma unroll
      for (int mi = 0; mi < 2; ++mi) {
        int row = wid * 32 + mi * 16 + c;
        a[mi] = *(const bf16x8*)&Qs[ks][row * 32 + (g ^ ((row >> 1) & 3)) * 8];
      }
#pragma unroll
      for (int nj = 0; nj < 8; ++nj) {
        int row = nj * 16 + c;
        bfr[nj] = *(const bf16x8*)&Ks[ks][row * 32 + (g ^ ((row >> 1) & 3)) * 8];
      }
#pragma unroll
      for (int mi = 0; mi < 2; ++mi)
#pragma unroll
        for (int nj = 0; nj < 8; ++nj)
          sacc[mi][nj] = __builtin_amdgcn_mfma_f32_16x16x32_bf16(a[mi], bfr[nj], sacc[mi][nj], 0, 0, 0);
    }
#pragma unroll
    for (int mi = 0; mi < 2; ++mi)
#pragma unroll
      for (int r = 0; r < 4; ++r) {
        int i = i0 + wid * 32 + mi * 16 + g * 4 + r;
        const uint4 mw = *(const uint4*)(Mrow + (size_t)i * 64);
#pragma unroll
        for (int nj = 0; nj < 8; ++nj) {
          uint32_t w = (nj < 2) ? mw.x : (nj < 4) ? mw.y : (nj < 6) ? mw.z : mw.w;
          bool bit = (w >> ((nj & 1) * 16 + c)) & 1u;
          float se = bit ? negr[nj] : sacc[mi][nj][r] * rjl2[nj];
          l_[nj] += exp2f(se);
        }
      }
  }
#pragma unroll
  for (int nj = 0; nj < 8; ++nj) {
    float l = l_[nj];
    l += __shfl_xor(l, 16);
    l += __shfl_xor(l, 32);
    if (g == 0) redL[wid][nj * 16 + c] = l;
  }
  __syncthreads();
  if (tid < 128) {
    float L = redL[0][tid] + redL[1][tid] + redL[2][tid] + redL[3][tid];
    float r = ratio_f[b_ * NN + j0 + tid];
    RZ[(size_t)bh * NN + j0 + tid] = make_float2(r * 0.125f * LOG2E, log2f(L));
  }
}

// ---------- pass 2: S^T = mfma(K,Q) -> packed b64 P-writes -> PV ----------
__global__ __launch_bounds__(256, 2)
void attn_pv(const uint16_t* __restrict__ qb, const uint16_t* __restrict__ kb,
             const uint16_t* __restrict__ vt, const uint32_t* __restrict__ mbits,
             const float2* __restrict__ RZ, uint16_t* __restrict__ ctxr) {
  __shared__ uint16_t Qs[2][128 * 32];
  __shared__ uint16_t Ks[2][128 * 32];
  __shared__ uint16_t Vs[4][64 * 32];
  __shared__ uint16_t Ps[128 * 128];   // row i: 128 bf16; 16B-granule XOR (i&7)
  const int tid = threadIdx.x, wid = tid >> 6, lane = tid & 63;
  const int g = lane >> 4, c = lane & 15;
  const int bh = blockIdx.x, b_ = bh >> 4, h = bh & 15;
  const int i0 = blockIdx.y * 128;
  const uint16_t* Qg = qb + (size_t)bh * NN * DD;
  const uint16_t* Kg = kb + (size_t)bh * NN * DD;
  const uint16_t* Vg = vt + (size_t)bh * DD * NN;
  const uint32_t* Mb = mbits + (size_t)b_ * NN * 64;
  const float2* RZb = RZ + (size_t)bh * NN;
#pragma unroll
  for (int hf = 0; hf < 2; ++hf)
#pragma unroll
    for (int is = 0; is < 2; ++is) {
      int sb = is * 256 + wid * 64;
      int s = sb + lane;
      int r = s >> 2, kp = s & 3;
      int kps = kp ^ ((r >> 1) & 3);
      gload16(&Qs[hf][sb * 8], Qg + (size_t)(i0 + r) * 64 + hf * 32 + kps * 8);
    }
  f32x4 cacc[2][4] = {};
  for (int j0 = 0; j0 < NN; j0 += 128) {
    __syncthreads();
#pragma unroll
    for (int hf = 0; hf < 2; ++hf)
#pragma unroll
      for (int is = 0; is < 2; ++is) {
        int sb = is * 256 + wid * 64;
        int s = sb + lane;
        int r = s >> 2, kp = s & 3;
        int kps = kp ^ ((r >> 1) & 3);
        gload16(&Ks[hf][sb * 8], Kg + (size_t)(j0 + r) * 64 + hf * 32 + kps * 8);
      }
#pragma unroll
    for (int vq = 0; vq < 4; ++vq) {
      int sb = wid * 64;
      int s = sb + lane;
      int d = s >> 2, kp = s & 3;
      int kps = kp ^ ((d >> 1) & 3);
      gload16(&Vs[vq][sb * 8], Vg + (size_t)d * NN + j0 + vq * 32 + kps * 8);
    }
    __syncthreads();
    // S^T: A = K rows (j), B = Q rows (i).  st[nj][mi]: lane holds
    // j = nj*16 + g*4 + reg (4 contiguous), i = wid*32 + mi*16 + c.
    f32x4 st[8][2] = {};
#pragma unroll
    for (int ks = 0; ks < 2; ++ks) {
      bf16x8 qf[2], kf[8];
#pragma unroll
      for (int mi = 0; mi < 2; ++mi) {
        int row = wid * 32 + mi * 16 + c;
        qf[mi] = *(const bf16x8*)&Qs[ks][row * 32 + (g ^ ((row >> 1) & 3)) * 8];
      }
#pragma unroll
      for (int nj = 0; nj < 8; ++nj) {
        int row = nj * 16 + c;
        kf[nj] = *(const bf16x8*)&Ks[ks][row * 32 + (g ^ ((row >> 1) & 3)) * 8];
      }
#pragma unroll
      for (int nj = 0; nj < 8; ++nj)
#pragma unroll
        for (int mi = 0; mi < 2; ++mi)
          st[nj][mi] = __builtin_amdgcn_mfma_f32_16x16x32_bf16(kf[nj], qf[mi], st[nj][mi], 0, 0, 0);
    }
    // masks: one uint4 per mi (covers 128 j bits at row i)
    uint4 mw0 = *(const uint4*)(Mb + (size_t)(i0 + wid * 32 + c) * 64 + (j0 >> 5));
    uint4 mw1 = *(const uint4*)(Mb + (size_t)(i0 + wid * 32 + 16 + c) * 64 + (j0 >> 5));
#pragma unroll
    for (int nj = 0; nj < 8; ++nj) {
      int jj = nj * 16 + g * 4;
      const float4* rzp = (const float4*)(RZb + j0 + jj);
      float4 rz01 = rzp[0], rz23 = rzp[1];
      float rj[4] = {rz01.x, rz01.z, rz23.x, rz23.z};
      float zj[4] = {rz01.y, rz01.w, rz23.y, rz23.w};
      float nz[4];
#pragma unroll
      for (int t = 0; t < 4; ++t) nz[t] = fmaf(rj[t], -8e9f, -zj[t]);
      int shbase = (nj & 1) * 16 + g * 4;
#pragma unroll
      for (int mi = 0; mi < 2; ++mi) {
        const uint4 mw = mi ? mw1 : mw0;
        uint32_t w = (nj < 2) ? mw.x : (nj < 4) ? mw.y : (nj < 6) ? mw.z : mw.w;
        float p[4];
#pragma unroll
        for (int t = 0; t < 4; ++t) {
          bool bit = (w >> (shbase + t)) & 1u;
          float se = bit ? nz[t] : fmaf(st[nj][mi][t], rj[t], -zj[t]);
          p[t] = exp2f(se);
        }
        uint32_t lo, hi;
        asm("v_cvt_pk_bf16_f32 %0, %1, %2" : "=v"(lo) : "v"(p[0]), "v"(p[1]));
        asm("v_cvt_pk_bf16_f32 %0, %1, %2" : "=v"(hi) : "v"(p[2]), "v"(p[3]));
        int iL = wid * 32 + mi * 16 + c;
        int gran = (nj * 2 + (g >> 1)) ^ (iL & 7);
        *(uint2*)((char*)Ps + iL * 256 + gran * 16 + (g & 1) * 8) = make_uint2(lo, hi);
      }
    }
    __syncthreads();
#pragma unroll
    for (int ks = 0; ks < 4; ++ks) {
      bf16x8 pa[2], vb[4];
#pragma unroll
      for (int mi = 0; mi < 2; ++mi) {
        int row = wid * 32 + mi * 16 + c;
        int gran = (ks * 4 + g) ^ (row & 7);
        pa[mi] = *(const bf16x8*)((const char*)Ps + row * 256 + gran * 16);
      }
#pragma unroll
      for (int nd = 0; nd < 4; ++nd) {
        int row = nd * 16 + c;
        vb[nd] = *(const bf16x8*)&Vs[ks][row * 32 + (g ^ ((row >> 1) & 3)) * 8];
      }
#pragma unroll
      for (int mi = 0; mi < 2; ++mi)
#pragma unroll
        for (int nd = 0; nd < 4; ++nd)
          cacc[mi][nd] = __builtin_amdgcn_mfma_f32_16x16x32_bf16(pa[mi], vb[nd], cacc[mi][nd], 0, 0, 0);
    }
  }
#pragma unroll
  for (int mi = 0; mi < 2; ++mi)
#pragma unroll
    for (int nd = 0; nd < 4; ++nd)
#pragma unroll
      for (int r = 0; r < 4; ++r) {
        int i = i0 + wid * 32 + mi * 16 + g * 4 + r;
        int d = nd * 16 + c;
        ctxr[((size_t)(b_ * NN + i)) * CC + h * DD + d] = f2bf(cacc[mi][nd][r]);
      }
}

// ---------- LayerNorm over C=1024 ----------
__global__ __launch_bounds__(256)
void ln_kernel(const float* __restrict__ xbuf, const void* __restrict__ gamma,
               const void* __restrict__ beta, float* __restrict__ out,
               const int* __restrict__ flags) {
  const int row = blockIdx.x;
  const int tid = threadIdx.x;
  const float4 v = ((const float4*)(xbuf + (size_t)row * CC))[tid];
  float s = v.x + v.y + v.z + v.w;
  float s2 = v.x * v.x + v.y * v.y + v.z * v.z + v.w * v.w;
#pragma unroll
  for (int off = 32; off >= 1; off >>= 1) {
    s += __shfl_xor(s, off);
    s2 += __shfl_xor(s2, off);
  }
  __shared__ float red[8];
  const int wid = tid >> 6, lane = tid & 63;
  if (lane == 0) { red[wid] = s; red[4 + wid] = s2; }
  __syncthreads();
  float ts = red[0] + red[1] + red[2] + red[3];
  float ts2 = red[4] + red[5] + red[6] + red[7];
  float mu = ts * (1.f / 1024.f);
  float var = ts2 * (1.f / 1024.f) - mu * mu;
  float rs = rsqrtf(var + 1e-5f);
  const int f32in = flags[0];
  const int cbase = tid * 4;
  float4 o;
  o.x = (v.x - mu) * rs * load_in_f(gamma, cbase + 0, f32in) + load_in_f(beta, cbase + 0, f32in);
  o.y = (v.y - mu) * rs * load_in_f(gamma, cbase + 1, f32in) + load_in_f(beta, cbase + 1, f32in);
  o.z = (v.z - mu) * rs * load_in_f(gamma, cbase + 2, f32in) + load_in_f(beta, cbase + 2, f32in);
  o.w = (v.w - mu) * rs * load_in_f(gamma, cbase + 3, f32in) + load_in_f(beta, cbase + 3, f32in);
  ((float4*)(out + (size_t)row * CC))[tid] = o;
}

// ---------- host ----------
extern "C" void kernel_launch(void* const* d_in, const int* in_sizes, int n_in,
                              void* d_out, int out_size, void* d_ws, size_t ws_size,
                              hipStream_t stream) {
  (void)in_sizes; (void)n_in; (void)out_size; (void)ws_size;
  char* ws = (char*)d_ws;
  size_t off = 0;
  auto alloc = [&](size_t bytes) -> void* {
    void* p = ws + off;
    off += (bytes + 255) & ~(size_t)255;
    return p;
  };
  int*      flags   = (int*)alloc(256);
  float2*   RZ      = (float2*)alloc((size_t)BB * HH * NN * 8);
  float*    ratio_f = (float*)alloc((size_t)BB * NN * 4);
  uint32_t* mbits   = (uint32_t*)alloc((size_t)BB * NN * 64 * 4);   // 2 MB bit mask
  uint16_t* xq      = (uint16_t*)alloc((size_t)BB * NN * CC * 2);
  uint16_t* xk      = (uint16_t*)alloc((size_t)BB * NN * CC * 2);
  uint16_t* xv      = (uint16_t*)alloc((size_t)BB * NN * CC * 2);
  uint16_t* qb      = (uint16_t*)alloc((size_t)BB * NN * CC * 2);
  uint16_t* kb      = (uint16_t*)alloc((size_t)BB * NN * CC * 2);
  uint16_t* vtb     = (uint16_t*)alloc((size_t)BB * NN * CC * 2);
  uint16_t* Wt      = (uint16_t*)alloc((size_t)4 * CC * CC * 2);
  uint16_t* ctxr    = xq;              // xq dead after Q projection
  float*    xbuf    = (float*)xk;      // xk+xv contiguous 32MB, dead after K/V proj

  detect_kernel<<<1, 64, 0, stream>>>((const uint32_t*)d_in[0], (const uint32_t*)d_in[4], flags);
  conv_bf16_3<<<dim3(2048, 1, 3), 256, 0, stream>>>(d_in[0], d_in[1], d_in[2],
                                                    xq, xk, xv, BB * NN * CC, flags);
  conv_ratio<<<32, 256, 0, stream>>>(d_in[3], ratio_f, BB * NN, flags);
  conv_maskbits<<<2048, 256, 0, stream>>>(d_in[4], mbits, BB * NN * NN, flags);
  transW<<<dim3(32, 32, 4), dim3(32, 8), 0, stream>>>(d_in[5], d_in[6], d_in[7], d_in[8], Wt, flags);

  gemm128<0><<<dim3(64, 8), 256, 0, stream>>>(xq, Wt,               qb,  nullptr, flags);
  gemm128<0><<<dim3(64, 8), 256, 0, stream>>>(xk, Wt + 1 * CC * CC, kb,  nullptr, flags);
  gemm128<1><<<dim3(64, 8), 256, 0, stream>>>(xv, Wt + 2 * CC * CC, vtb, nullptr, flags);

  attn_stats<<<dim3(64, 16), 256, 0, stream>>>(qb, kb, mbits, ratio_f, RZ);
  attn_pv<<<dim3(64, 16), 256, 0, stream>>>(qb, kb, vtb, mbits, RZ, ctxr);

  gemm128<2><<<dim3(64, 8), 256, 0, stream>>>(ctxr, Wt + 3 * CC * CC, xbuf, d_in[0], flags);
  ln_kernel<<<8192, 256, 0, stream>>>(xbuf, d_in[9], d_in[10], (float*)d_out, flags);
}